// Round 5
// baseline (355.974 us; speedup 1.0000x reference)
//
#include <hip/hip_runtime.h>

#define DD 64          // node embedding dim
#define RR 8           // num relations
#define KA 576         // (RR+1)*DD : agg rows 0..7 + x as "relation 8"
#define NT 18          // K steps = KA/32
#define NPART 8        // dst partitions ~ XCDs (blockIdx%8 round-robin)
#define ECH 2048       // edges per slice-block in partitioned kernels

typedef short bf16x8 __attribute__((ext_vector_type(8)));   // 8 bf16
typedef float f32x4  __attribute__((ext_vector_type(4)));

__device__ __forceinline__ float bf2f(unsigned short u) {
    union { unsigned u; float f; } c; c.u = ((unsigned)u) << 16; return c.f;
}
__device__ __forceinline__ unsigned short f2bf(float f) {
    union { float f; unsigned u; } c; c.f = f;
    unsigned u = c.u;
    u += 0x7FFF + ((u >> 16) & 1);      // round-to-nearest-even
    return (unsigned short)(u >> 16);
}

// ---------------------------------------------------------------------------
// Partitioned count: partition p (= blockIdx%8 -> XCD p) owns dst range
// [N*p/8, N*(p+1)/8). cnt cell = dst*RR + rel.
// ---------------------------------------------------------------------------
__global__ __launch_bounds__(256) void k_count_part(
    const int* __restrict__ ei, const int* __restrict__ et,
    int* __restrict__ cnt, int E, int N)
{
    const int p   = blockIdx.x & (NPART - 1);
    const int sb  = blockIdx.x / NPART;
    const int dlo = (int)((long long)N * p / NPART);
    const int dhi = (int)((long long)N * (p + 1) / NPART);
    const int e0  = sb * ECH;
    const int e1  = min(E, e0 + ECH);
    for (int e = e0 + threadIdx.x; e < e1; e += 256) {
        int dst = ei[E + e];
        if (dst >= dlo && dst < dhi)
            atomicAdd(&cnt[(size_t)dst * RR + et[e]], 1);
    }
}

// ---------------------------------------------------------------------------
// Bucket allocation over ALL N*RR cells: start2[cell] = bucket offset.
// Block-local in-order scan + one global atomic per block. Cells of one dst
// (8 consecutive) always land in one block (8 | 256) -> a dst's 8 runs are
// contiguous and rel-ordered in `sorted`.
// ---------------------------------------------------------------------------
__global__ __launch_bounds__(256) void k_alloc2(
    const int* __restrict__ cnt, int* __restrict__ start2,
    int* __restrict__ head2, int* __restrict__ counter, int M)
{
    __shared__ int sdata[256];
    __shared__ int sbase;
    const int tid = threadIdx.x;
    const int n = blockIdx.x * 256 + tid;

    int deg = (n < M) ? cnt[n] : 0;
    sdata[tid] = deg;
    __syncthreads();
    int v = deg;
    #pragma unroll
    for (int off = 1; off < 256; off <<= 1) {
        int t = (tid >= off) ? sdata[tid - off] : 0;
        __syncthreads();
        v += t;
        sdata[tid] = v;
        __syncthreads();
    }
    if (tid == 255) sbase = atomicAdd(counter, v);
    __syncthreads();
    if (n < M) {
        int st = sbase + v - deg;
        start2[n] = st;
        head2[n]  = st;
    }
}

// ---------------------------------------------------------------------------
// Partitioned bucket scatter into (dst,rel) cells: sorted[pos] = src.
// ---------------------------------------------------------------------------
__global__ __launch_bounds__(256) void k_bucket_part(
    const int* __restrict__ ei, const int* __restrict__ et,
    int* __restrict__ head2, int* __restrict__ sorted, int E, int N)
{
    const int p   = blockIdx.x & (NPART - 1);
    const int sb  = blockIdx.x / NPART;
    const int dlo = (int)((long long)N * p / NPART);
    const int dhi = (int)((long long)N * (p + 1) / NPART);
    const int e0  = sb * ECH;
    const int e1  = min(E, e0 + ECH);
    for (int e = e0 + threadIdx.x; e < e1; e += 256) {
        int dst = ei[E + e];
        if (dst >= dlo && dst < dhi) {
            int pos = atomicAdd(&head2[(size_t)dst * RR + et[e]], 1);
            sorted[pos] = ei[e];
        }
    }
}

// ---------------------------------------------------------------------------
// Pack Wcat = [W_rel(8) ; W_root] into MFMA-B fragment order, bf16 hi + lo.
// ---------------------------------------------------------------------------
__global__ void k_packW(const float* __restrict__ Wrel, const float* __restrict__ Wroot,
                        unsigned short* __restrict__ Bh, unsigned short* __restrict__ Bl)
{
    int idx = blockIdx.x * 256 + threadIdx.x;
    if (idx >= NT * 4 * 64 * 8) return;
    int i    = idx & 7;
    int lane = (idx >> 3) & 63;
    int f    = (idx >> 9) & 3;
    int t    = idx >> 11;
    int k = t * 32 + (lane >> 4) * 8 + i;
    int d = f * 16 + (lane & 15);
    int r = k >> 6, kk = k & 63;
    float w = (r < RR) ? Wrel[((size_t)r * DD + kk) * DD + d]
                       : Wroot[(size_t)kk * DD + d];
    unsigned short h = f2bf(w);
    Bh[idx] = h;
    Bl[idx] = f2bf(w - bf2f(h));
}

// ---------------------------------------------------------------------------
// One wave per dst. Edges are rel-sorted: per rel run, gather-accumulate
// x rows with SGPR-base loads (src via readlane from a cooperatively-loaded
// 64-edge index window). No selects: ~2 VALU + 1 VMEM per edge.
// ---------------------------------------------------------------------------
__global__ __launch_bounds__(256) void k_aggregate(
    const float* __restrict__ x, const int* __restrict__ sorted,
    const int* __restrict__ start2, const int* __restrict__ cnt2,
    unsigned short* __restrict__ agg, int c0, int c1)
{
    const int dst = c0 + blockIdx.x * 4 + (threadIdx.x >> 6);
    if (dst >= c1) return;
    const int lane = threadIdx.x & 63;
    const int cell = dst * RR;

    const int s0 = __builtin_amdgcn_readfirstlane(start2[cell]);
    int cs[RR];
    int deg = 0;
    #pragma unroll
    for (int r = 0; r < RR; ++r) {
        cs[r] = __builtin_amdgcn_readfirstlane(cnt2[cell + r]);
        deg += cs[r];
    }
    const int end = s0 + deg;

    // index window [wbase, wbase+64)
    int wbase = s0;
    int vidx = (wbase + lane < end) ? sorted[wbase + lane] : 0;

    unsigned short* ao = agg + (size_t)(dst - c0) * KA + lane;
    int e = s0;

    #pragma unroll 1
    for (int r = 0; r < RR; ++r) {
        int c = cs[r];
        float acc = 0.f;
        while (c > 0) {
            if (e - wbase >= 64) {               // slide window
                wbase = e;
                vidx = (wbase + lane < end) ? sorted[wbase + lane] : 0;
            }
            const int k = e - wbase;             // uniform
            const int take = min(c, 64 - k);
            int i = 0;
            for (; i + 1 < take; i += 2) {
                int s1 = __builtin_amdgcn_readlane(vidx, k + i);
                int s2 = __builtin_amdgcn_readlane(vidx, k + i + 1);
                float u = x[(size_t)s1 * DD + lane];
                float w = x[(size_t)s2 * DD + lane];
                acc += u;
                acc += w;
            }
            if (i < take) {
                int s1 = __builtin_amdgcn_readlane(vidx, k + i);
                acc += x[(size_t)s1 * DD + lane];
            }
            e += take;
            c -= take;
        }
        ao[r * DD] = f2bf(acc * (1.f / fmaxf((float)cs[r], 1.f)));
    }
    ao[8 * DD] = f2bf(x[(size_t)dst * DD + lane]);
}

// ---------------------------------------------------------------------------
// out[64-node tile] = A(64x576) @ (Bh + Bl)(576x64) + bias   via MFMA bf16.
// ---------------------------------------------------------------------------
__global__ __launch_bounds__(256) void k_transform_mfma(
    const unsigned short* __restrict__ A,
    const unsigned short* __restrict__ Bh,
    const unsigned short* __restrict__ Bl,
    const float* __restrict__ bias,
    float* __restrict__ out, int c0, int c1)
{
    const int nb   = c0 + blockIdx.x * 64;
    const int wv   = threadIdx.x >> 6;
    const int lane = threadIdx.x & 63;
    const int rlo  = lane & 15;        // A row within 16 / D col within 16
    const int kg   = lane >> 4;        // k-group

    const unsigned short* ap = A + ((size_t)(nb - c0) + wv * 16 + rlo) * KA + kg * 8;

    f32x4 acc0 = {0.f,0.f,0.f,0.f};
    f32x4 acc1 = {0.f,0.f,0.f,0.f};
    f32x4 acc2 = {0.f,0.f,0.f,0.f};
    f32x4 acc3 = {0.f,0.f,0.f,0.f};

    #pragma unroll
    for (int t = 0; t < NT; ++t) {
        bf16x8 a = *(const bf16x8*)(ap + t * 32);
        const unsigned short* bh = Bh + (size_t)t * 2048 + lane * 8;
        const unsigned short* bl = Bl + (size_t)t * 2048 + lane * 8;
        bf16x8 b;
        b = *(const bf16x8*)(bh +    0); acc0 = __builtin_amdgcn_mfma_f32_16x16x32_bf16(a, b, acc0, 0, 0, 0);
        b = *(const bf16x8*)(bh +  512); acc1 = __builtin_amdgcn_mfma_f32_16x16x32_bf16(a, b, acc1, 0, 0, 0);
        b = *(const bf16x8*)(bh + 1024); acc2 = __builtin_amdgcn_mfma_f32_16x16x32_bf16(a, b, acc2, 0, 0, 0);
        b = *(const bf16x8*)(bh + 1536); acc3 = __builtin_amdgcn_mfma_f32_16x16x32_bf16(a, b, acc3, 0, 0, 0);
        b = *(const bf16x8*)(bl +    0); acc0 = __builtin_amdgcn_mfma_f32_16x16x32_bf16(a, b, acc0, 0, 0, 0);
        b = *(const bf16x8*)(bl +  512); acc1 = __builtin_amdgcn_mfma_f32_16x16x32_bf16(a, b, acc1, 0, 0, 0);
        b = *(const bf16x8*)(bl + 1024); acc2 = __builtin_amdgcn_mfma_f32_16x16x32_bf16(a, b, acc2, 0, 0, 0);
        b = *(const bf16x8*)(bl + 1536); acc3 = __builtin_amdgcn_mfma_f32_16x16x32_bf16(a, b, acc3, 0, 0, 0);
    }

    // C/D layout: col = lane&15, row = (lane>>4)*4 + reg
    const float b0 = bias[rlo];
    const float b1 = bias[rlo + 16];
    const float b2 = bias[rlo + 32];
    const float b3 = bias[rlo + 48];
    const int orow = nb + wv * 16 + kg * 4;
    #pragma unroll
    for (int j = 0; j < 4; ++j) {
        int r = orow + j;
        if (r < c1) {
            float* op = out + (size_t)r * DD + rlo;
            op[0]  = acc0[j] + b0;
            op[16] = acc1[j] + b1;
            op[32] = acc2[j] + b2;
            op[48] = acc3[j] + b3;
        }
    }
}

// ---------------------------------------------------------------------------
// echo edge_index / edge_type into d_out tail as float
// ---------------------------------------------------------------------------
__global__ void k_echo(const int* __restrict__ ei, const int* __restrict__ et,
                       float* __restrict__ out_ei, float* __restrict__ out_et,
                       int E)
{
    int i = blockIdx.x * 256 + threadIdx.x;
    if (i < 2 * E) out_ei[i] = (float)ei[i];
    if (i < E)     out_et[i] = (float)et[i];
}

extern "C" void kernel_launch(void* const* d_in, const int* in_sizes, int n_in,
                              void* d_out, int out_size, void* d_ws, size_t ws_size,
                              hipStream_t stream)
{
    const float* x     = (const float*)d_in[0];
    const int*   ei    = (const int*)d_in[1];
    const int*   et    = (const int*)d_in[2];
    const float* Wrel  = (const float*)d_in[3];
    const float* Wroot = (const float*)d_in[4];
    const float* bias  = (const float*)d_in[5];

    const int N = in_sizes[0] / DD;
    const int E = in_sizes[2];
    const int M = N * RR;                        // (dst, rel) cells

    float* out    = (float*)d_out;
    float* out_ei = out + (size_t)N * DD;
    float* out_et = out_ei + (size_t)2 * E;

    auto align = [](size_t v) { return (v + 255) & ~(size_t)255; };

    // workspace layout
    size_t p = 0;
    int* cnt = (int*)((char*)d_ws + p);              p += align((size_t)M * 4);
    int* counter = (int*)((char*)d_ws + p);
    size_t zero_bytes = p + 256;                     p += 256;
    int* start2 = (int*)((char*)d_ws + p);           p += align((size_t)M * 4);
    int* head2  = (int*)((char*)d_ws + p);           p += align((size_t)M * 4);
    int* sorted = (int*)((char*)d_ws + p);           p += align((size_t)E * 4);
    unsigned short* Bh = (unsigned short*)((char*)d_ws + p); p += align((size_t)NT*4*64*8*2);
    unsigned short* Bl = (unsigned short*)((char*)d_ws + p); p += align((size_t)NT*4*64*8*2);
    unsigned short* agg = (unsigned short*)((char*)d_ws + p);
    size_t avail = (ws_size > p) ? ws_size - p : 0;

    const size_t per_node = (size_t)KA * 2;          // 1152 B
    int chunk = (int)(((avail / per_node) - 64) & ~(size_t)63);
    if (chunk > N) chunk = (N + 63) & ~(size_t)63;
    if (chunk < 64) chunk = 64;

    hipMemsetAsync(d_ws, 0, zero_bytes, stream);     // cnt + counter

    const int nsb = (E + ECH - 1) / ECH;             // slice-blocks per partition

    k_packW <<<dim3((NT*4*64*8 + 255) / 256), 256, 0, stream>>>(Wrel, Wroot, Bh, Bl);
    k_count_part <<<dim3(nsb * NPART), 256, 0, stream>>>(ei, et, cnt, E, N);
    k_alloc2<<<dim3((M + 255) / 256), 256, 0, stream>>>(cnt, start2, head2, counter, M);
    k_bucket_part<<<dim3(nsb * NPART), 256, 0, stream>>>(ei, et, head2, sorted, E, N);

    for (int c0 = 0; c0 < N; c0 += chunk) {
        int c1 = min(N, c0 + chunk);
        int nc = c1 - c0;
        k_aggregate     <<<dim3((nc + 3) / 4),   256, 0, stream>>>(
            x, sorted, start2, cnt, agg, c0, c1);
        k_transform_mfma<<<dim3((nc + 63) / 64), 256, 0, stream>>>(
            agg, Bh, Bl, bias, out, c0, c1);
    }

    k_echo<<<dim3((2 * E + 255) / 256), 256, 0, stream>>>(ei, et, out_ei, out_et, E);
}

// Round 6
// 315.280 us; speedup vs baseline: 1.1291x; 1.1291x over previous
//
#include <hip/hip_runtime.h>

#define DD 64          // node embedding dim
#define RR 8           // num relations
#define KA 576         // (RR+1)*DD : agg rows 0..7 + x as "relation 8"
#define NT 18          // K steps = KA/32
#define NPART 8        // dst partitions ~ XCDs (blockIdx%8 round-robin)
#define ECH 2048       // edges per slice-block in partitioned kernels

typedef short bf16x8 __attribute__((ext_vector_type(8)));   // 8 bf16
typedef float f32x4  __attribute__((ext_vector_type(4)));

__device__ __forceinline__ float bf2f(unsigned short u) {
    union { unsigned u; float f; } c; c.u = ((unsigned)u) << 16; return c.f;
}
__device__ __forceinline__ unsigned short f2bf(float f) {
    union { float f; unsigned u; } c; c.f = f;
    unsigned u = c.u;
    u += 0x7FFF + ((u >> 16) & 1);      // round-to-nearest-even
    return (unsigned short)(u >> 16);
}

// ---------------------------------------------------------------------------
// x -> bf16 rows; row N is an all-zero pad row (targets of dummy pad edges).
// ---------------------------------------------------------------------------
__global__ void k_xcast(const float* __restrict__ x, unsigned short* __restrict__ xb,
                        int N)
{
    int i = blockIdx.x * 256 + threadIdx.x;              // quad index
    int total = (N + 1) * (DD / 4);
    if (i >= total) return;
    ushort4 o;
    if (i < N * (DD / 4)) {
        float4 f = ((const float4*)x)[i];
        o = make_ushort4(f2bf(f.x), f2bf(f.y), f2bf(f.z), f2bf(f.w));
    } else {
        o = make_ushort4(0, 0, 0, 0);
    }
    ((ushort4*)xb)[i] = o;
}

// ---------------------------------------------------------------------------
// Partitioned count: partition p (= blockIdx%8 -> XCD p) owns dst range
// [N*p/8, N*(p+1)/8). cnt cell = dst*RR + rel.
// ---------------------------------------------------------------------------
__global__ __launch_bounds__(256) void k_count_part(
    const int* __restrict__ ei, const int* __restrict__ et,
    int* __restrict__ cnt, int E, int N)
{
    const int p   = blockIdx.x & (NPART - 1);
    const int sb  = blockIdx.x / NPART;
    const int dlo = (int)((long long)N * p / NPART);
    const int dhi = (int)((long long)N * (p + 1) / NPART);
    const int e0  = sb * ECH;
    const int e1  = min(E, e0 + ECH);
    for (int e = e0 + threadIdx.x; e < e1; e += 256) {
        int dst = ei[E + e];
        if (dst >= dlo && dst < dhi)
            atomicAdd(&cnt[(size_t)dst * RR + et[e]], 1);
    }
}

// ---------------------------------------------------------------------------
// Per-dst bucket allocation, padded to a multiple of 4 edges. Pad entries
// (src=N -> zero row, rel=0) are written here so the gather loop is
// unconditional 4-wide.
// ---------------------------------------------------------------------------
__global__ __launch_bounds__(256) void k_alloc(
    const int* __restrict__ cnt, int* __restrict__ startv,
    int* __restrict__ headv, int* __restrict__ counter,
    int* __restrict__ sorted, int N)
{
    __shared__ int sdata[256];
    __shared__ int sbase;
    const int tid = threadIdx.x;
    const int n = blockIdx.x * 256 + tid;

    int deg = 0, deg4 = 0;
    if (n < N) {
        const int4* c4 = (const int4*)(cnt + (size_t)n * RR);
        int4 a = c4[0], b = c4[1];
        deg  = a.x + a.y + a.z + a.w + b.x + b.y + b.z + b.w;
        deg4 = (deg + 3) & ~3;
    }
    sdata[tid] = deg4;
    __syncthreads();
    int v = deg4;
    #pragma unroll
    for (int off = 1; off < 256; off <<= 1) {
        int t = (tid >= off) ? sdata[tid - off] : 0;
        __syncthreads();
        v += t;
        sdata[tid] = v;
        __syncthreads();
    }
    if (tid == 255) sbase = atomicAdd(counter, v);
    __syncthreads();
    if (n < N) {
        int st = sbase + v - deg4;
        startv[n] = st;
        headv[n]  = st;
        for (int j = deg; j < deg4; ++j) sorted[st + j] = N;   // pad -> zero row
    }
}

// ---------------------------------------------------------------------------
// Partitioned bucket scatter: sorted[pos] = src | (rel << 24).
// ---------------------------------------------------------------------------
__global__ __launch_bounds__(256) void k_bucket_part(
    const int* __restrict__ ei, const int* __restrict__ et,
    int* __restrict__ headv, int* __restrict__ sorted, int E, int N)
{
    const int p   = blockIdx.x & (NPART - 1);
    const int sb  = blockIdx.x / NPART;
    const int dlo = (int)((long long)N * p / NPART);
    const int dhi = (int)((long long)N * (p + 1) / NPART);
    const int e0  = sb * ECH;
    const int e1  = min(E, e0 + ECH);
    for (int e = e0 + threadIdx.x; e < e1; e += 256) {
        int dst = ei[E + e];
        if (dst >= dlo && dst < dhi) {
            int pos = atomicAdd(&headv[dst], 1);
            sorted[pos] = ei[e] | (et[e] << 24);
        }
    }
}

// ---------------------------------------------------------------------------
// Pack Wcat = [W_rel(8) ; W_root] into MFMA-B fragment order, bf16 hi + lo.
// ---------------------------------------------------------------------------
__global__ void k_packW(const float* __restrict__ Wrel, const float* __restrict__ Wroot,
                        unsigned short* __restrict__ Bh, unsigned short* __restrict__ Bl)
{
    int idx = blockIdx.x * 256 + threadIdx.x;
    if (idx >= NT * 4 * 64 * 8) return;
    int i    = idx & 7;
    int lane = (idx >> 3) & 63;
    int f    = (idx >> 9) & 3;
    int t    = idx >> 11;
    int k = t * 32 + (lane >> 4) * 8 + i;
    int d = f * 16 + (lane & 15);
    int r = k >> 6, kk = k & 63;
    float w = (r < RR) ? Wrel[((size_t)r * DD + kk) * DD + d]
                       : Wroot[(size_t)kk * DD + d];
    unsigned short h = f2bf(w);
    Bh[idx] = h;
    Bl[idx] = f2bf(w - bf2f(h));
}

// ---------------------------------------------------------------------------
// One wave per dst. Padded flat edge stream (multiple of 4): per 4 edges,
// 4 readlane -> scalar (src,rel), 4 independent bf16 gathers in flight,
// then uniform-condition routing into 8 named accumulators. Normalization
// once per dst in the epilogue.
// ---------------------------------------------------------------------------
__global__ __launch_bounds__(256) void k_aggregate(
    const unsigned short* __restrict__ xb, const int* __restrict__ sorted,
    const int* __restrict__ startv, const int* __restrict__ cnt,
    unsigned short* __restrict__ agg, int c0, int c1)
{
    const int dst = c0 + blockIdx.x * 4 + (threadIdx.x >> 6);
    if (dst >= c1) return;
    const int lane = threadIdx.x & 63;

    const int4* c4 = (const int4*)(cnt + (size_t)dst * RR);
    const int4 ca = c4[0], cb = c4[1];
    int deg  = ca.x + ca.y + ca.z + ca.w + cb.x + cb.y + cb.z + cb.w;
    int deg4 = (deg + 3) & ~3;
    const int s0  = __builtin_amdgcn_readfirstlane(startv[dst]);
    const int end = s0 + __builtin_amdgcn_readfirstlane(deg4);

    float a0=0.f,a1=0.f,a2=0.f,a3=0.f,a4=0.f,a5=0.f,a6=0.f,a7=0.f;

    int wbase = s0;
    int vidx  = sorted[wbase + lane];
    int e = s0;
    while (e < end) {
        if (e - wbase >= 64) {                 // slide 64-edge index window
            wbase = e;
            vidx  = sorted[wbase + lane];
        }
        const int k    = e - wbase;            // uniform, multiple of 4
        const int take = min(end - e, 64 - k); // multiple of 4
        for (int i = 0; i < take; i += 4) {
            int p0 = __builtin_amdgcn_readlane(vidx, k + i);
            int p1 = __builtin_amdgcn_readlane(vidx, k + i + 1);
            int p2 = __builtin_amdgcn_readlane(vidx, k + i + 2);
            int p3 = __builtin_amdgcn_readlane(vidx, k + i + 3);
            int q0 = p0 & 0xFFFFFF, r0 = p0 >> 24;
            int q1 = p1 & 0xFFFFFF, r1 = p1 >> 24;
            int q2 = p2 & 0xFFFFFF, r2 = p2 >> 24;
            int q3 = p3 & 0xFFFFFF, r3 = p3 >> 24;
            float v0 = bf2f(xb[(size_t)q0 * DD + lane]);
            float v1 = bf2f(xb[(size_t)q1 * DD + lane]);
            float v2 = bf2f(xb[(size_t)q2 * DD + lane]);
            float v3 = bf2f(xb[(size_t)q3 * DD + lane]);
            if      (r0==0) a0+=v0; else if (r0==1) a1+=v0; else if (r0==2) a2+=v0;
            else if (r0==3) a3+=v0; else if (r0==4) a4+=v0; else if (r0==5) a5+=v0;
            else if (r0==6) a6+=v0; else a7+=v0;
            if      (r1==0) a0+=v1; else if (r1==1) a1+=v1; else if (r1==2) a2+=v1;
            else if (r1==3) a3+=v1; else if (r1==4) a4+=v1; else if (r1==5) a5+=v1;
            else if (r1==6) a6+=v1; else a7+=v1;
            if      (r2==0) a0+=v2; else if (r2==1) a1+=v2; else if (r2==2) a2+=v2;
            else if (r2==3) a3+=v2; else if (r2==4) a4+=v2; else if (r2==5) a5+=v2;
            else if (r2==6) a6+=v2; else a7+=v2;
            if      (r3==0) a0+=v3; else if (r3==1) a1+=v3; else if (r3==2) a2+=v3;
            else if (r3==3) a3+=v3; else if (r3==4) a4+=v3; else if (r3==5) a5+=v3;
            else if (r3==6) a6+=v3; else a7+=v3;
        }
        e += take;
    }

    unsigned short* ao = agg + (size_t)(dst - c0) * KA + lane;
    ao[0*DD] = f2bf(a0 * (1.f / fmaxf((float)ca.x, 1.f)));
    ao[1*DD] = f2bf(a1 * (1.f / fmaxf((float)ca.y, 1.f)));
    ao[2*DD] = f2bf(a2 * (1.f / fmaxf((float)ca.z, 1.f)));
    ao[3*DD] = f2bf(a3 * (1.f / fmaxf((float)ca.w, 1.f)));
    ao[4*DD] = f2bf(a4 * (1.f / fmaxf((float)cb.x, 1.f)));
    ao[5*DD] = f2bf(a5 * (1.f / fmaxf((float)cb.y, 1.f)));
    ao[6*DD] = f2bf(a6 * (1.f / fmaxf((float)cb.z, 1.f)));
    ao[7*DD] = f2bf(a7 * (1.f / fmaxf((float)cb.w, 1.f)));
    ao[8*DD] = xb[(size_t)dst * DD + lane];       // x row, already bf16
}

// ---------------------------------------------------------------------------
// out[64-node tile] = A(64x576) @ (Bh + Bl)(576x64) + bias   via MFMA bf16.
// ---------------------------------------------------------------------------
__global__ __launch_bounds__(256) void k_transform_mfma(
    const unsigned short* __restrict__ A,
    const unsigned short* __restrict__ Bh,
    const unsigned short* __restrict__ Bl,
    const float* __restrict__ bias,
    float* __restrict__ out, int c0, int c1)
{
    const int nb   = c0 + blockIdx.x * 64;
    const int wv   = threadIdx.x >> 6;
    const int lane = threadIdx.x & 63;
    const int rlo  = lane & 15;        // A row within 16 / D col within 16
    const int kg   = lane >> 4;        // k-group

    const unsigned short* ap = A + ((size_t)(nb - c0) + wv * 16 + rlo) * KA + kg * 8;

    f32x4 acc0 = {0.f,0.f,0.f,0.f};
    f32x4 acc1 = {0.f,0.f,0.f,0.f};
    f32x4 acc2 = {0.f,0.f,0.f,0.f};
    f32x4 acc3 = {0.f,0.f,0.f,0.f};

    #pragma unroll
    for (int t = 0; t < NT; ++t) {
        bf16x8 a = *(const bf16x8*)(ap + t * 32);
        const unsigned short* bh = Bh + (size_t)t * 2048 + lane * 8;
        const unsigned short* bl = Bl + (size_t)t * 2048 + lane * 8;
        bf16x8 b;
        b = *(const bf16x8*)(bh +    0); acc0 = __builtin_amdgcn_mfma_f32_16x16x32_bf16(a, b, acc0, 0, 0, 0);
        b = *(const bf16x8*)(bh +  512); acc1 = __builtin_amdgcn_mfma_f32_16x16x32_bf16(a, b, acc1, 0, 0, 0);
        b = *(const bf16x8*)(bh + 1024); acc2 = __builtin_amdgcn_mfma_f32_16x16x32_bf16(a, b, acc2, 0, 0, 0);
        b = *(const bf16x8*)(bh + 1536); acc3 = __builtin_amdgcn_mfma_f32_16x16x32_bf16(a, b, acc3, 0, 0, 0);
        b = *(const bf16x8*)(bl +    0); acc0 = __builtin_amdgcn_mfma_f32_16x16x32_bf16(a, b, acc0, 0, 0, 0);
        b = *(const bf16x8*)(bl +  512); acc1 = __builtin_amdgcn_mfma_f32_16x16x32_bf16(a, b, acc1, 0, 0, 0);
        b = *(const bf16x8*)(bl + 1024); acc2 = __builtin_amdgcn_mfma_f32_16x16x32_bf16(a, b, acc2, 0, 0, 0);
        b = *(const bf16x8*)(bl + 1536); acc3 = __builtin_amdgcn_mfma_f32_16x16x32_bf16(a, b, acc3, 0, 0, 0);
    }

    // C/D layout: col = lane&15, row = (lane>>4)*4 + reg
    const float b0 = bias[rlo];
    const float b1 = bias[rlo + 16];
    const float b2 = bias[rlo + 32];
    const float b3 = bias[rlo + 48];
    const int orow = nb + wv * 16 + kg * 4;
    #pragma unroll
    for (int j = 0; j < 4; ++j) {
        int r = orow + j;
        if (r < c1) {
            float* op = out + (size_t)r * DD + rlo;
            op[0]  = acc0[j] + b0;
            op[16] = acc1[j] + b1;
            op[32] = acc2[j] + b2;
            op[48] = acc3[j] + b3;
        }
    }
}

// ---------------------------------------------------------------------------
// echo edge_index / edge_type into d_out tail as float
// ---------------------------------------------------------------------------
__global__ void k_echo(const int* __restrict__ ei, const int* __restrict__ et,
                       float* __restrict__ out_ei, float* __restrict__ out_et,
                       int E)
{
    int i = blockIdx.x * 256 + threadIdx.x;
    if (i < 2 * E) out_ei[i] = (float)ei[i];
    if (i < E)     out_et[i] = (float)et[i];
}

extern "C" void kernel_launch(void* const* d_in, const int* in_sizes, int n_in,
                              void* d_out, int out_size, void* d_ws, size_t ws_size,
                              hipStream_t stream)
{
    const float* x     = (const float*)d_in[0];
    const int*   ei    = (const int*)d_in[1];
    const int*   et    = (const int*)d_in[2];
    const float* Wrel  = (const float*)d_in[3];
    const float* Wroot = (const float*)d_in[4];
    const float* bias  = (const float*)d_in[5];

    const int N = in_sizes[0] / DD;
    const int E = in_sizes[2];
    const int M = N * RR;

    float* out    = (float*)d_out;
    float* out_ei = out + (size_t)N * DD;
    float* out_et = out_ei + (size_t)2 * E;

    auto align = [](size_t v) { return (v + 255) & ~(size_t)255; };

    // workspace layout
    size_t p = 0;
    int* cnt = (int*)((char*)d_ws + p);              p += align((size_t)M * 4);
    int* counter = (int*)((char*)d_ws + p);
    size_t zero_bytes = p + 256;                     p += 256;
    int* startv = (int*)((char*)d_ws + p);           p += align((size_t)N * 4);
    int* headv  = (int*)((char*)d_ws + p);           p += align((size_t)N * 4);
    int* sorted = (int*)((char*)d_ws + p);           p += align(((size_t)E + 3*(size_t)N + 128) * 4);
    unsigned short* xb = (unsigned short*)((char*)d_ws + p); p += align(((size_t)N + 1) * DD * 2);
    unsigned short* Bh = (unsigned short*)((char*)d_ws + p); p += align((size_t)NT*4*64*8*2);
    unsigned short* Bl = (unsigned short*)((char*)d_ws + p); p += align((size_t)NT*4*64*8*2);
    unsigned short* agg = (unsigned short*)((char*)d_ws + p);
    size_t avail = (ws_size > p) ? ws_size - p : 0;

    const size_t per_node = (size_t)KA * 2;          // 1152 B
    int chunk = (int)(((avail / per_node) - 64) & ~(size_t)63);
    if (chunk > N) chunk = (N + 63) & ~(size_t)63;
    if (chunk < 64) chunk = 64;

    hipMemsetAsync(d_ws, 0, zero_bytes, stream);     // cnt + counter

    const int nsb = (E + ECH - 1) / ECH;             // slice-blocks per partition

    k_xcast <<<dim3(((N + 1) * (DD/4) + 255) / 256), 256, 0, stream>>>(x, xb, N);
    k_packW <<<dim3((NT*4*64*8 + 255) / 256), 256, 0, stream>>>(Wrel, Wroot, Bh, Bl);
    k_count_part <<<dim3(nsb * NPART), 256, 0, stream>>>(ei, et, cnt, E, N);
    k_alloc <<<dim3((N + 255) / 256), 256, 0, stream>>>(cnt, startv, headv,
                                                        counter, sorted, N);
    k_bucket_part<<<dim3(nsb * NPART), 256, 0, stream>>>(ei, et, headv, sorted, E, N);

    for (int c0 = 0; c0 < N; c0 += chunk) {
        int c1 = min(N, c0 + chunk);
        int nc = c1 - c0;
        k_aggregate     <<<dim3((nc + 3) / 4),   256, 0, stream>>>(
            xb, sorted, startv, cnt, agg, c0, c1);
        k_transform_mfma<<<dim3((nc + 63) / 64), 256, 0, stream>>>(
            agg, Bh, Bl, bias, out, c0, c1);
    }

    k_echo<<<dim3((2 * E + 255) / 256), 256, 0, stream>>>(ei, et, out_ei, out_et, E);
}